// Round 8
// baseline (471.249 us; speedup 1.0000x reference)
//
#include <hip/hip_runtime.h>
#include <math.h>

#define PI_F 3.14159265358979323846f

typedef __attribute__((ext_vector_type(8))) short short8;
typedef __attribute__((ext_vector_type(4))) float f32x4;

__device__ __forceinline__ unsigned short f2bf(float f) {
    unsigned int u = __float_as_uint(f);
    unsigned int r = (u + 0x7fffu + ((u >> 16) & 1u)) >> 16;
    return (unsigned short)r;
}
__device__ __forceinline__ float bf2f(unsigned short v) {
    return __uint_as_float((unsigned int)v << 16);
}

// ---------------- encoder: x[16][8192][2] -> u1 bf16 [64][16][8192] ----------------
__global__ __launch_bounds__(256) void enc_kernel(
    const float* __restrict__ x, const float* __restrict__ ew,
    const float* __restrict__ eb, unsigned short* __restrict__ u1)
{
    int idx = blockIdx.x * 256 + threadIdx.x;   // 64*16*2048 threads, 4 t each
    int t4 = idx & 2047;
    int b  = (idx >> 11) & 15;
    int h  = idx >> 15;
    float w0 = ew[2*h], w1 = ew[2*h+1], bb = eb[h];
    const float* xp = x + ((size_t)b*8192 + (size_t)t4*4)*2;
    float4 a = *(const float4*)xp;
    float4 c = *(const float4*)(xp + 4);
    ushort4 o;
    o.x = f2bf(fmaf(w0, a.x, fmaf(w1, a.y, bb)));
    o.y = f2bf(fmaf(w0, a.z, fmaf(w1, a.w, bb)));
    o.z = f2bf(fmaf(w0, c.x, fmaf(w1, c.y, bb)));
    o.w = f2bf(fmaf(w0, c.z, fmaf(w1, c.w, bb)));
    *(ushort4*)(u1 + ((size_t)h*16 + b)*8192 + (size_t)t4*4) = o;
}

// ---------------- conv weight prep: fp32 [O][Cin][3] -> bf16 A-frag [kb][o][kk] ------
__global__ __launch_bounds__(256) void prep_w(
    const float* __restrict__ w0, const float* __restrict__ w1,
    const float* __restrict__ w2, const float* __restrict__ w3,
    const float* __restrict__ w4, const float* __restrict__ w5,
    const float* __restrict__ w6, const float* __restrict__ w7,
    unsigned short* __restrict__ wprep)
{
    int id = blockIdx.y;
    const float* src; int Cin; size_t doff;
    switch (id) {
        case 0: src = w0; Cin = 64;  doff = 0;      break;
        case 1: src = w1; Cin = 64;  doff = 12288;  break;
        case 2: src = w2; Cin = 64;  doff = 24576;  break;
        case 3: src = w3; Cin = 64;  doff = 36864;  break;
        case 4: src = w4; Cin = 256; doff = 49152;  break;
        case 5: src = w5; Cin = 256; doff = 245760; break;
        case 6: src = w6; Cin = 256; doff = 442368; break;
        default: src = w7; Cin = 256; doff = 638976; break;
    }
    int e = blockIdx.x * 256 + threadIdx.x;
    if (e >= Cin * Cin * 3) return;
    int kb  = e / (Cin * 32);
    int rem = e - kb * (Cin * 32);
    int o   = rem >> 5;
    int kk  = rem & 31;
    int cch = kb / 6, t6 = kb % 6, k = t6 >> 1, chalf = t6 & 1;
    int c = cch * 64 + chalf * 32 + kk;
    wprep[doff + e] = f2bf(src[((size_t)o * Cin + c) * 3 + k]);
}

// ---------------- S4 prep: build per-h MFMA A-matrices (coalesced writes) ----------
__global__ __launch_bounds__(128) void prep_s4(
    const float* __restrict__ log_dt, const float* __restrict__ C2,
    const float* __restrict__ Dv,
    unsigned short* __restrict__ TA, unsigned short* __restrict__ VA,
    float* __restrict__ rs, float* __restrict__ Vrs)
{
    int h = blockIdx.x, t = threadIdx.x;
    __shared__ float cn[64];
    __shared__ float sK[128];
    __shared__ unsigned short s_w[128 * 66];   // W staged [m][j], pad 66
    float dt = expf(log_dt[h]);
    if (t < 32) {
        int n = t;
        float e = expf(-0.5f*dt);
        float s_, c_; sincosf(PI_F*dt*n, &s_, &c_);
        float wr = e*c_, wi = e*s_;
        float ar = -0.5f, ai = PI_F*n;
        float den = 1.f/(ar*ar + ai*ai);
        float tr = wr - 1.f, ti = wi;
        float qr = (tr*ar + ti*ai)*den;
        float qi = (ti*ar - tr*ai)*den;
        float c2r = C2[((size_t)h*32+n)*2], c2i = C2[((size_t)h*32+n)*2+1];
        cn[2*n]   = 2.f*(c2r*qr - c2i*qi);
        cn[2*n+1] = 2.f*(c2r*qi + c2i*qr);
        float e128 = expf(-64.f*dt);
        float s2, c2v; sincosf(PI_F*dt*n*128.f, &s2, &c2v);
        float pr = 1.f - e128*c2v, pim = -e128*s2;
        float dr = 1.f - wr, di = -wi;
        float dd = 1.f/(dr*dr + di*di);
        Vrs[(size_t)h*64 + 2*n]   = (pr*dr + pim*di)*dd;
        Vrs[(size_t)h*64 + 2*n+1] = (pim*dr - pr*di)*dd;
    }
    __syncthreads();
    {
        float em = expf(-0.5f*dt*t);
        float Kt = 0.f;
        for (int n = 0; n < 32; n++) {
            float s_, c_; sincosf(PI_F*dt*(float)(n*t), &s_, &c_);
            Kt += cn[2*n]*em*c_ - cn[2*n+1]*em*s_;
        }
        sK[t] = Kt + (t == 0 ? Dv[h] : 0.f);
    }
    if (t < 64) {
        int n = t >> 1, ri = t & 1;
        float e = expf(-0.5f*dt);
        float s_, c_; sincosf(PI_F*dt*n, &s_, &c_);
        float wr = e*c_, wi = e*s_;
        float crn = cn[2*n], cin = cn[2*n+1];
        float pr = wr, pim = wi;
        for (int m = 0; m < 128; m++) {
            float re = crn*pr - cin*pim;
            float im = crn*pim + cin*pr;
            s_w[m*66 + t] = f2bf(ri ? -im : re);
            float nr = pr*wr - pim*wi;
            float ni = pr*wi + pim*wr;
            pr = nr; pim = ni;
        }
    } else {
        int r = t - 64; int n = r >> 1, ri = r & 1;
        float e = expf(-0.5f*dt);
        float s_, c_; sincosf(PI_F*dt*n, &s_, &c_);
        float wr = e*c_, wi = e*s_;
        float cr2 = 1.f, ci2 = 0.f;
        for (int kb = 3; kb >= 0; kb--) {
            unsigned short buf[32];
            for (int kk = 31; kk >= 0; kk--) {
                buf[kk] = f2bf(ri ? ci2 : cr2);
                float nr = cr2*wr - ci2*wi;
                float ni = cr2*wi + ci2*wr;
                cr2 = nr; ci2 = ni;
            }
            uint4* dst = (uint4*)&VA[(((size_t)h*4 + kb)*64 + r)*32];
            uint4* src = (uint4*)buf;
            dst[0]=src[0]; dst[1]=src[1]; dst[2]=src[2]; dst[3]=src[3];
        }
    }
    __syncthreads();
    {
        float acc = 0.f;
        for (int tau = 0; tau <= t; tau++) acc += sK[tau];
        rs[(size_t)h*128 + t] = acc;
    }
    for (int kb = 0; kb < 4; kb++) {
        unsigned short tb[32];
#pragma unroll
        for (int kk = 0; kk < 32; kk++) {
            int col = kb*32 + kk;
            tb[kk] = f2bf((col <= t) ? sK[t - col] : 0.f);
        }
        uint4* dst = (uint4*)&TA[(((size_t)h*6 + kb)*128 + t)*32];
        uint4* src = (uint4*)tb;
        dst[0]=src[0]; dst[1]=src[1]; dst[2]=src[2]; dst[3]=src[3];
    }
    for (int i = t; i < 1024; i += 128) {
        int kb = i >> 9;
        int rem = i & 511;
        int m = rem >> 2, kkg = rem & 3;
        *(uint4*)&TA[(((size_t)h*6 + 4 + kb)*128 + m)*32 + kkg*8] =
            *(const uint4*)&s_w[m*66 + kb*32 + kkg*8];
    }
}

// ---------------- slim prep (s4c): V rows + rowsums, coalesced ----------------
__global__ __launch_bounds__(64) void prep_va(
    const float* __restrict__ log_dt,
    unsigned short* __restrict__ VA, float* __restrict__ Vrs)
{
    int h = blockIdx.x, t = threadIdx.x;     // t = row = 2n+ri
    int n = t >> 1, ri = t & 1;
    float dt = expf(log_dt[h]);
    float e = expf(-0.5f*dt);
    float s_, c_; sincosf(PI_F*dt*n, &s_, &c_);
    float wr = e*c_, wi = e*s_;
    float cr2 = 1.f, ci2 = 0.f;
    for (int kb = 3; kb >= 0; kb--) {
        unsigned short buf[32];
        for (int kk = 31; kk >= 0; kk--) {
            buf[kk] = f2bf(ri ? ci2 : cr2);
            float nr = cr2*wr - ci2*wi;
            float ni = cr2*wi + ci2*wr;
            cr2 = nr; ci2 = ni;
        }
        uint4* dst = (uint4*)&VA[(((size_t)h*4 + kb)*64 + t)*32];
        uint4* src = (uint4*)buf;
        dst[0]=src[0]; dst[1]=src[1]; dst[2]=src[2]; dst[3]=src[3];
    }
    if (ri == 0) {
        float e128 = expf(-64.f*dt);
        float s2, c2v; sincosf(PI_F*dt*n*128.f, &s2, &c2v);
        float pr = 1.f - e128*c2v, pim = -e128*s2;
        float dr = 1.f - wr, di = -wi;
        float dd = 1.f/(dr*dr + di*di);
        Vrs[(size_t)h*64 + 2*n]   = (pr*dr + pim*di)*dd;
        Vrs[(size_t)h*64 + 2*n+1] = (pim*dr - pr*di)*dd;
    }
}

// ---------------- S4 pass A (GEMM): chunk end-states E = V @ u ----------------
template<int NCH, int LOGNCH>
__global__ __launch_bounds__(64) void s4_gemm_a(
    const unsigned short* __restrict__ u, const unsigned short* __restrict__ VA,
    const float* __restrict__ Vrs, const float* __restrict__ sc,
    const float* __restrict__ sh, float* __restrict__ Bc)
{
    const int L = NCH * 128;
    int h = blockIdx.y;
    int lane = threadIdx.x;
    int nl = lane & 15, g = lane >> 4;
    int col = blockIdx.x * 16 + nl;
    int b = col >> LOGNCH, c = col & (NCH - 1);
    const unsigned short* up = u + ((size_t)h*16 + b)*L + c*128;
    f32x4 acc[4];
#pragma unroll
    for (int mt = 0; mt < 4; mt++) acc[mt] = (f32x4){0.f,0.f,0.f,0.f};
#pragma unroll
    for (int kb = 0; kb < 4; kb++) {
        short8 bf = *(const short8*)(up + kb*32 + g*8);
#pragma unroll
        for (int mt = 0; mt < 4; mt++) {
            short8 af = *(const short8*)(VA + (((size_t)h*4 + kb)*64 + mt*16 + nl)*32 + g*8);
            acc[mt] = __builtin_amdgcn_mfma_f32_16x16x32_bf16(af, bf, acc[mt], 0, 0, 0);
        }
    }
    float scv = sc ? sc[h] : 1.f;
    float shv = sh ? sh[h] : 0.f;
    float* bp = Bc + (((size_t)h*16 + b)*NCH + c)*64;
#pragma unroll
    for (int mt = 0; mt < 4; mt++) {
        int j0 = mt*16 + g*4;
        float4 vr = *(const float4*)(Vrs + (size_t)h*64 + j0);
        float4 o;
        o.x = fmaf(scv, acc[mt][0], shv*vr.x);
        o.y = fmaf(scv, acc[mt][1], shv*vr.y);
        o.z = fmaf(scv, acc[mt][2], shv*vr.z);
        o.w = fmaf(scv, acc[mt][3], shv*vr.w);
        *(float4*)(bp + j0) = o;
    }
}

// ---------------- S4 mid: chunk-level scan (w^128 via 7 squarings) ----------------
__global__ __launch_bounds__(64) void s4_mid(
    const float* __restrict__ log_dt, const float* __restrict__ Bc,
    float* __restrict__ Sinit, float* __restrict__ Sfinal,
    int H, int NCH)
{
    int gid = blockIdx.x * 64 + threadIdx.x;   // H*16*32
    int n = gid & 31;
    int tmp = gid >> 5;
    int b = tmp & 15;
    int h = tmp >> 4;
    float dt = expf(log_dt[h]);
    float e = expf(-0.5f * dt);
    float s_, c_; sincosf(PI_F * dt * n, &s_, &c_);
    float wr = e * c_, wi = e * s_;
#pragma unroll
    for (int i = 0; i < 7; i++) { float r = wr*wr - wi*wi; float im = 2.f*wr*wi; wr = r; wi = im; }
    float Sr = 0.f, Si = 0.f;
    size_t base = (((size_t)h*16 + b)*NCH)*64 + 2*n;
    for (int c = 0; c < NCH; c++) {
        float2 v; v.x = Sr; v.y = Si;
        *(float2*)(Sinit + base + (size_t)c*64) = v;
        float2 bc = *(const float2*)(Bc + base + (size_t)c*64);
        float r  = fmaf(wr, Sr, fmaf(-wi, Si, bc.x));
        float im = fmaf(wi, Sr, fmaf( wr, Si, bc.y));
        Sr = r; Si = im;
    }
    if (Sfinal) {
        float2 v; v.x = Sr; v.y = Si;
        *(float2*)(Sfinal + ((size_t)h*16 + b)*64 + 2*n) = v;
    }
}

// ---------------- S4 pass C (GEMM): y = sc*(T'@u) + sh*rs + W@Sinit ----------------
template<int NCH, int LOGNCH>
__global__ __launch_bounds__(256) void s4_gemm_c(
    const unsigned short* __restrict__ u, const float* __restrict__ Sini,
    const unsigned short* __restrict__ TA, const float* __restrict__ rs,
    const float* __restrict__ sc, const float* __restrict__ sh,
    unsigned short* __restrict__ yout)
{
    const int L = NCH * 128;
    __shared__ unsigned short s_u[64*200];   // 25600 B
    __shared__ unsigned short s_s[64*72];    // 9216 B
    int h = blockIdx.y;
    int tid = threadIdx.x;
    int lane = tid & 63, wid = tid >> 6;
    int nl = lane & 15, g = lane >> 4;
    int col0 = blockIdx.x * 64;
    for (int i = tid; i < 1024; i += 256) {
        int cl = i >> 4, o = i & 15;
        int col = col0 + cl; int b = col >> LOGNCH, c = col & (NCH - 1);
        *(uint4*)&s_u[cl*200 + o*8] =
            *(const uint4*)&u[((size_t)h*16 + b)*L + c*128 + o*8];
    }
    for (int i = tid; i < 1024; i += 256) {
        int cl = i >> 4, o = i & 15;
        int col = col0 + cl; int b = col >> LOGNCH, c = col & (NCH - 1);
        float4 v = *(const float4*)&Sini[(((size_t)h*16 + b)*NCH + c)*64 + o*4];
        ushort4 q; q.x = f2bf(v.x); q.y = f2bf(v.y); q.z = f2bf(v.z); q.w = f2bf(v.w);
        *(ushort4*)&s_s[cl*72 + o*4] = q;
    }
    __syncthreads();
    f32x4 accT[2][4], accW[2][4];
#pragma unroll
    for (int a = 0; a < 2; a++)
#pragma unroll
        for (int j = 0; j < 4; j++) { accT[a][j] = (f32x4){0,0,0,0}; accW[a][j] = (f32x4){0,0,0,0}; }
#pragma unroll
    for (int kb = 0; kb < 4; kb++) {
        short8 bfr[4];
#pragma unroll
        for (int j = 0; j < 4; j++)
            bfr[j] = *(const short8*)&s_u[(j*16 + nl)*200 + kb*32 + g*8];
#pragma unroll
        for (int mt2 = 0; mt2 < 2; mt2++) {
            int mtile = wid*2 + mt2;
            short8 af = *(const short8*)&TA[(((size_t)h*6 + kb)*128 + mtile*16 + nl)*32 + g*8];
#pragma unroll
            for (int j = 0; j < 4; j++)
                accT[mt2][j] = __builtin_amdgcn_mfma_f32_16x16x32_bf16(af, bfr[j], accT[mt2][j], 0, 0, 0);
        }
    }
#pragma unroll
    for (int kw = 0; kw < 2; kw++) {
        short8 bfr[4];
#pragma unroll
        for (int j = 0; j < 4; j++)
            bfr[j] = *(const short8*)&s_s[(j*16 + nl)*72 + kw*32 + g*8];
#pragma unroll
        for (int mt2 = 0; mt2 < 2; mt2++) {
            int mtile = wid*2 + mt2;
            short8 af = *(const short8*)&TA[(((size_t)h*6 + 4 + kw)*128 + mtile*16 + nl)*32 + g*8];
#pragma unroll
            for (int j = 0; j < 4; j++)
                accW[mt2][j] = __builtin_amdgcn_mfma_f32_16x16x32_bf16(af, bfr[j], accW[mt2][j], 0, 0, 0);
        }
    }
    float scv = sc ? sc[h] : 1.f;
    float shv = sh ? sh[h] : 0.f;
#pragma unroll
    for (int mt2 = 0; mt2 < 2; mt2++) {
        int m0 = (wid*2 + mt2)*16 + g*4;
        float4 rsv = *(const float4*)&rs[(size_t)h*128 + m0];
#pragma unroll
        for (int j = 0; j < 4; j++) {
            int col = col0 + j*16 + nl; int b = col >> LOGNCH, c = col & (NCH - 1);
            ushort4 q;
            q.x = f2bf(fmaf(scv, accT[mt2][j][0], shv*rsv.x) + accW[mt2][j][0]);
            q.y = f2bf(fmaf(scv, accT[mt2][j][1], shv*rsv.y) + accW[mt2][j][1]);
            q.z = f2bf(fmaf(scv, accT[mt2][j][2], shv*rsv.z) + accW[mt2][j][2]);
            q.w = f2bf(fmaf(scv, accT[mt2][j][3], shv*rsv.w) + accW[mt2][j][3]);
            *(ushort4*)&yout[((size_t)h*16 + b)*L + c*128 + m0] = q;
        }
    }
}

// ---------------- fused 4-dilation conv block via MFMA (v4) ----------------
// block = 32 o x 64 t x 4 d (og split across z for 2x grid / 4 blocks/CU).
// waves: wave = 16 o x 32 t x 4 d; ow = wid&1, fh = wid>>1.
// ch-fast staging (conflict-free writes), PWP=74 padded rows, reg prefetch.
template<int CIN>
__global__ __launch_bounds__(256, 4) void conv_mfma4(
    const unsigned short* __restrict__ u, const unsigned short* __restrict__ wp,
    const float* __restrict__ bs0, const float* __restrict__ bs1,
    const float* __restrict__ bs2, const float* __restrict__ bs3,
    unsigned short* __restrict__ out, int Lin, int Lout)
{
    constexpr int NR = CIN / 64;
    constexpr int PWP = 74;                    // padded row (ushorts), 37 words
    __shared__ unsigned short s_in[4*68*PWP];  // 40256 B -> 4 blocks/CU
    int tid = threadIdx.x;
    int lane = tid & 63, wid = tid >> 6;
    int ow = wid & 1, fh = wid >> 1;
    int nl = lane & 15, g = lane >> 4;
    int t0 = blockIdx.x * 64;
    int b  = blockIdx.y;
    int og = blockIdx.z * 32;
    const int P0 = t0 * 4 - 8;

    f32x4 acc[4][2];   // [d][f]
#pragma unroll
    for (int d = 0; d < 4; d++)
#pragma unroll
        for (int f = 0; f < 2; f++) acc[d][f] = (f32x4){0.f,0.f,0.f,0.f};

    // staging descriptors: i = tid + 256*j; ch = i & 63 (lane order), po = i >> 6
    unsigned short stg[9][8];
    int sch[9], spo[9];
#pragma unroll
    for (int j = 0; j < 9; j++) { int i = tid + 256*j; sch[j] = i & 63; spo[j] = i >> 6; }
    const bool v8 = (tid < 128);   // 2176 slots; slot 8 valid for tid<128

    // prologue: load round 0
#pragma unroll
    for (int j = 0; j < 9; j++) {
        if (j == 8 && !v8) continue;
        int p = P0 + spo[j]*8;
        const unsigned short* gp = u + ((size_t)sch[j]*16 + b)*Lin;
        if (p >= 0 && p + 8 <= Lin) {
            *(uint4*)stg[j] = *(const uint4*)(gp + p);
        } else {
#pragma unroll
            for (int jj = 0; jj < 8; jj++) {
                int pj = p + jj;
                stg[j][jj] = ((unsigned)pj < (unsigned)Lin) ? gp[pj] : (unsigned short)0;
            }
        }
    }

    for (int cc = 0; cc < NR; cc++) {
        if (cc) __syncthreads();
#pragma unroll
        for (int j = 0; j < 9; j++) {
            if (j == 8 && !v8) continue;
#pragma unroll
            for (int jj = 0; jj < 8; jj++)
                s_in[((jj&3)*68 + spo[j]*2 + (jj>>2))*PWP + sch[j]] = stg[j][jj];
        }
        __syncthreads();
        if (cc + 1 < NR) {
#pragma unroll
            for (int j = 0; j < 9; j++) {
                if (j == 8 && !v8) continue;
                int p = P0 + spo[j]*8;
                const unsigned short* gp = u + ((size_t)((cc+1)*64 + sch[j])*16 + b)*Lin;
                if (p >= 0 && p + 8 <= Lin) {
                    *(uint4*)stg[j] = *(const uint4*)(gp + p);
                } else {
#pragma unroll
                    for (int jj = 0; jj < 8; jj++) {
                        int pj = p + jj;
                        stg[j][jj] = ((unsigned)pj < (unsigned)Lin) ? gp[pj] : (unsigned short)0;
                    }
                }
            }
        }
#pragma unroll
        for (int k = 0; k < 3; ++k) {
#pragma unroll
            for (int chalf = 0; chalf < 2; ++chalf) {
                int kb = cc*6 + k*2 + chalf;
                short8 af[4];
#pragma unroll
                for (int d = 0; d < 4; d++)
                    af[d] = *(const short8*)&wp[(size_t)d*(3*CIN*CIN) +
                        ((size_t)kb*CIN + og + ow*16 + nl)*32 + g*8];
                if (k == 1) {
                    short8 bf[2];
#pragma unroll
                    for (int f = 0; f < 2; f++)
                        bf[f] = *(const short8*)&s_in[(fh*32 + f*16 + nl + 2)*PWP + chalf*32 + g*8];
#pragma unroll
                    for (int d = 0; d < 4; d++)
#pragma unroll
                        for (int f = 0; f < 2; f++)
                            acc[d][f] = __builtin_amdgcn_mfma_f32_16x16x32_bf16(
                                af[d], bf[f], acc[d][f], 0, 0, 0);
                } else {
#pragma unroll
                    for (int d = 0; d < 4; d++) {
                        const int off = (k - 1) * (1 << d) + 8;   // 0..16
                        const int r = off & 3, s = off >> 2;
#pragma unroll
                        for (int f = 0; f < 2; f++) {
                            short8 bf = *(const short8*)&s_in[
                                (r*68 + fh*32 + f*16 + nl + s)*PWP + chalf*32 + g*8];
                            acc[d][f] = __builtin_amdgcn_mfma_f32_16x16x32_bf16(
                                af[d], bf, acc[d][f], 0, 0, 0);
                        }
                    }
                }
            }
        }
    }
    const float* bptr[4] = {bs0, bs1, bs2, bs3};
#pragma unroll
    for (int d = 0; d < 4; ++d) {
#pragma unroll
        for (int f = 0; f < 2; ++f) {
            int t = t0 + fh*32 + f*16 + nl;
#pragma unroll
            for (int r2 = 0; r2 < 4; ++r2) {
                int o = og + ow*16 + g*4 + r2;
                float v = acc[d][f][r2] + bptr[d][o];
                if (d) v = v >= 0.f ? v : 0.3f*v;
                out[((size_t)(d*CIN + o)*16 + b)*Lout + t] = f2bf(v);
            }
        }
    }
}

// ---------------- BN stats, two-stage ----------------
__global__ __launch_bounds__(256) void bn_sum(
    const unsigned short* __restrict__ x, float* __restrict__ part, int n, int nseg)
{
    int ch = blockIdx.x, seg = blockIdx.y;
    int m = n / nseg;
    const unsigned short* xp = x + (size_t)ch*n + (size_t)seg*m;
    float s1 = 0.f, s2 = 0.f;
    for (int i = threadIdx.x*8; i < m; i += 2048) {
        uint4 raw = *(const uint4*)(xp + i);
        unsigned short us[8]; *(uint4*)us = raw;
#pragma unroll
        for (int j = 0; j < 8; j++) {
            float v = bf2f(us[j]);
            s1 += v; s2 += v*v;
        }
    }
    for (int o = 32; o > 0; o >>= 1) { s1 += __shfl_down(s1, o); s2 += __shfl_down(s2, o); }
    __shared__ float p1[4], p2[4];
    int wid = threadIdx.x >> 6;
    if ((threadIdx.x & 63) == 0) { p1[wid] = s1; p2[wid] = s2; }
    __syncthreads();
    if (threadIdx.x == 0) {
        part[((size_t)ch*nseg + seg)*2]     = p1[0] + p1[1] + p1[2] + p1[3];
        part[((size_t)ch*nseg + seg)*2 + 1] = p2[0] + p2[1] + p2[2] + p2[3];
    }
}

__global__ __launch_bounds__(64) void bn_fin(
    const float* __restrict__ part, const float* __restrict__ g,
    const float* __restrict__ bb, float* __restrict__ sc, float* __restrict__ sh,
    int n, int nseg, int gmask)
{
    int ch = blockIdx.x*64 + threadIdx.x;
    float s1 = 0.f, s2 = 0.f;
    for (int s = 0; s < nseg; s++) {
        s1 += part[((size_t)ch*nseg + s)*2];
        s2 += part[((size_t)ch*nseg + s)*2 + 1];
    }
    float m = s1 / n;
    float var = s2 / n - m*m;
    float rstd = rsqrtf(var + 1e-5f);
    float scale = g[ch & gmask] * rstd;
    sc[ch] = scale;
    sh[ch] = fmaf(-m, scale, bb[ch & gmask]);
}

// ---------------- s4c final-state -> x3[:, :, 511] ----------------
__global__ __launch_bounds__(256) void s4c_last(
    const float* __restrict__ Sfinal, const unsigned short* __restrict__ u3,
    const float* __restrict__ sc, const float* __restrict__ sh,
    const float* __restrict__ log_dt, const float* __restrict__ C2,
    const float* __restrict__ Dv, float* __restrict__ x3last)
{
    int gid = blockIdx.x*256 + threadIdx.x;  // 16*1024
    int h = gid & 1023;
    int b = gid >> 10;
    float dt = expf(log_dt[h]);
    float e = expf(-0.5f * dt);
    const float* sp = Sfinal + ((size_t)h*16 + b)*64;
    float aR = 0.f, aI = 0.f;
#pragma unroll
    for (int n = 0; n < 32; n++) {
        float s_, c_; sincosf(PI_F * dt * n, &s_, &c_);
        float wr = e*c_, wi = e*s_;
        float ar = -0.5f, ai = PI_F * n;
        float den = 1.f / (ar*ar + ai*ai);
        float tr = wr - 1.f, ti = wi;
        float qr = (tr*ar + ti*ai) * den;
        float qi = (ti*ar - tr*ai) * den;
        float c2r = C2[((size_t)h*32 + n)*2], c2i = C2[((size_t)h*32 + n)*2 + 1];
        float crv = c2r*qr - c2i*qi, civ = c2r*qi + c2i*qr;
        aR = fmaf(crv, sp[2*n],   aR);
        aI = fmaf(civ, sp[2*n+1], aI);
    }
    float uv = fmaf(sc[h], bf2f(u3[((size_t)h*16 + b)*512 + 511]), sh[h]);
    x3last[b*1024 + h] = 2.f*(aR - aI) + Dv[h]*uv;
}

// ---------------- decoder head ----------------
__global__ __launch_bounds__(256) void dec_kernel(
    const float* __restrict__ x3last, const float* __restrict__ w1, const float* __restrict__ b1,
    const float* __restrict__ w2, const float* __restrict__ b2, float* __restrict__ out)
{
    __shared__ float xs[1024];
    int b = blockIdx.x, tid = threadIdx.x;
    for (int i = tid; i < 1024; i += 256) xs[i] = x3last[b*1024 + i];
    __syncthreads();
    float z = b1[tid];
    const float* wpt = w1 + (size_t)tid*1024;
    for (int i = 0; i < 1024; i += 4) {
        float4 wv = *(const float4*)(wpt + i);
        z = fmaf(wv.x, xs[i],   z);
        z = fmaf(wv.y, xs[i+1], z);
        z = fmaf(wv.z, xs[i+2], z);
        z = fmaf(wv.w, xs[i+3], z);
    }
    float v = w2[tid] * z;
    for (int o = 32; o > 0; o >>= 1) v += __shfl_down(v, o);
    __shared__ float ps[4];
    if ((tid & 63) == 0) ps[tid >> 6] = v;
    __syncthreads();
    if (tid == 0) out[b] = ps[0] + ps[1] + ps[2] + ps[3] + b2[0];
}

extern "C" void kernel_launch(void* const* d_in, const int* in_sizes, int n_in,
                              void* d_out, int out_size, void* d_ws, size_t ws_size,
                              hipStream_t stream)
{
    const float* x       = (const float*)d_in[0];
    const float* enc_w   = (const float*)d_in[1];
    const float* enc_b   = (const float*)d_in[2];
    const float* s4a_ldt = (const float*)d_in[3];
    const float* s4a_C   = (const float*)d_in[4];
    const float* s4a_D   = (const float*)d_in[5];
    const float* s4b_ldt = (const float*)d_in[6];
    const float* s4b_C   = (const float*)d_in[7];
    const float* s4b_D   = (const float*)d_in[8];
    const float* s4c_ldt = (const float*)d_in[9];
    const float* s4c_C   = (const float*)d_in[10];
    const float* s4c_D   = (const float*)d_in[11];
    const float* b1w[4] = {(const float*)d_in[12], (const float*)d_in[14], (const float*)d_in[16], (const float*)d_in[18]};
    const float* b1b[4] = {(const float*)d_in[13], (const float*)d_in[15], (const float*)d_in[17], (const float*)d_in[19]};
    const float* b2w[4] = {(const float*)d_in[20], (const float*)d_in[22], (const float*)d_in[24], (const float*)d_in[26]};
    const float* b2b[4] = {(const float*)d_in[21], (const float*)d_in[23], (const float*)d_in[25], (const float*)d_in[27]};
    const float* bn1_g  = (const float*)d_in[28];
    const float* bn1_b  = (const float*)d_in[29];
    const float* bn2_g  = (const float*)d_in[30];
    const float* bn2_b  = (const float*)d_in[31];
    const float* dec1_w = (const float*)d_in[32];
    const float* dec1_b = (const float*)d_in[33];
    const float* dec2_w = (const float*)d_in[34];
    const float* dec2_b = (const float*)d_in[35];
    float* out = (float*)d_out;

    char* ws = (char*)d_ws;
    unsigned short* u1    = (unsigned short*)(ws);              // 16.8 MB (also u3)
    unsigned short* u3    = u1;
    unsigned short* ya    = (unsigned short*)(ws + 16777216);   // 16.8 MB (also yb, later VA_c)
    unsigned short* yb    = ya;
    unsigned short* VA_c  = ya;                                 // reuse after conv2
    unsigned short* u2    = (unsigned short*)(ws + 33554432);   // 16.8 MB
    float*          Bc    = (float*)(ws + 50331648);            // 16.8 MB
    float*          Sini  = (float*)(ws + 67108864);            // 16.8 MB
    float*          Sfin  = (float*)(ws + 83886080);            // 4.2 MB
    unsigned short* wprep = (unsigned short*)(ws + 88080384);   // 1.67 MB
    unsigned short* TA_a  = (unsigned short*)(ws + 89751552);   // 3.15 MB
    unsigned short* TA_b  = (unsigned short*)(ws + 92897280);   // 12.6 MB
    unsigned short* VA_a  = (unsigned short*)(ws + 105480192);  // 1.05 MB
    unsigned short* VA_b  = (unsigned short*)(ws + 106528768);  // 4.2 MB
    float*          rs_a  = (float*)(ws + 110723072);           // 32 KB
    float*          rs_b  = (float*)(ws + 110755840);           // 128 KB
    float*          Vrs_a = (float*)(ws + 110886912);           // 16 KB
    float*          Vrs_b = (float*)(ws + 110903296);           // 64 KB
    float*          smallp= (float*)(ws + 110968832);
    float* sc1 = smallp;         // 256
    float* sh1 = smallp + 256;   // 256
    float* sc2 = smallp + 512;   // 1024
    float* sh2 = smallp + 1536;  // 1024
    float* x3l = smallp + 2560;  // 16384
    float*          Vrs_c = (float*)(ws + 111280128);           // 256 KB
    float*          part1 = (float*)(ws + 111542272);           // 16 KB (256*8*2)
    float*          part2 = (float*)(ws + 111558656);           // 16 KB (1024*2*2)

    // prep (independent of data path)
    prep_w<<<dim3(768, 8), 256, 0, stream>>>(b1w[0], b1w[1], b1w[2], b1w[3],
                                             b2w[0], b2w[1], b2w[2], b2w[3], wprep);
    prep_s4<<<64, 128, 0, stream>>>(s4a_ldt, s4a_C, s4a_D, TA_a, VA_a, rs_a, Vrs_a);
    prep_s4<<<256, 128, 0, stream>>>(s4b_ldt, s4b_C, s4b_D, TA_b, VA_b, rs_b, Vrs_b);

    // encoder -> u1 bf16
    enc_kernel<<<8192, 256, 0, stream>>>(x, enc_w, enc_b, u1);

    // s4a: H=64, NCH=64 (L=8192)
    s4_gemm_a<64,6><<<dim3(64, 64), 64, 0, stream>>>(u1, VA_a, Vrs_a, nullptr, nullptr, Bc);
    s4_mid<<<512, 64, 0, stream>>>(s4a_ldt, Bc, Sini, nullptr, 64, 64);
    s4_gemm_c<64,6><<<dim3(16, 64), 256, 0, stream>>>(u1, Sini, TA_a, rs_a, nullptr, nullptr, ya);

    // conv block1 (fused 4 dilations, og-split): ya [64][16][8192] -> u2 [256][16][2048]
    conv_mfma4<64><<<dim3(32, 16, 2), 256, 0, stream>>>(
        ya, wprep, b1b[0], b1b[1], b1b[2], b1b[3], u2, 8192, 2048);
    bn_sum<<<dim3(256, 8), 256, 0, stream>>>(u2, part1, 16*2048, 8);
    bn_fin<<<4, 64, 0, stream>>>(part1, bn1_g, bn1_b, sc1, sh1, 16*2048, 8, 63);

    // s4b: H=256, NCH=16 (L=2048)
    s4_gemm_a<16,4><<<dim3(16, 256), 64, 0, stream>>>(u2, VA_b, Vrs_b, sc1, sh1, Bc);
    s4_mid<<<2048, 64, 0, stream>>>(s4b_ldt, Bc, Sini, nullptr, 256, 16);
    s4_gemm_c<16,4><<<dim3(4, 256), 256, 0, stream>>>(u2, Sini, TA_b, rs_b, sc1, sh1, yb);

    // conv block2 (fused 4 dilations, og-split): yb [256][16][2048] -> u3 [1024][16][512]
    conv_mfma4<256><<<dim3(8, 16, 8), 256, 0, stream>>>(
        yb, wprep + 49152, b2b[0], b2b[1], b2b[2], b2b[3], u3, 2048, 512);
    bn_sum<<<dim3(1024, 2), 256, 0, stream>>>(u3, part2, 16*512, 2);
    bn_fin<<<16, 64, 0, stream>>>(part2, bn2_g, bn2_b, sc2, sh2, 16*512, 2, 255);

    // s4c: H=1024, NCH=4 (L=512); only final state needed.
    prep_va<<<1024, 64, 0, stream>>>(s4c_ldt, VA_c, Vrs_c);
    s4_gemm_a<4,2><<<dim3(4, 1024), 64, 0, stream>>>(u3, VA_c, Vrs_c, sc2, sh2, Bc);
    s4_mid<<<8192, 64, 0, stream>>>(s4c_ldt, Bc, Sini, Sfin, 1024, 4);
    s4c_last<<<64, 256, 0, stream>>>(Sfin, u3, sc2, sh2, s4c_ldt, s4c_C, s4c_D, x3l);

    // decoder head
    dec_kernel<<<16, 256, 0, stream>>>(x3l, dec1_w, dec1_b, dec2_w, dec2_b, out);
}

// Round 9
// 428.165 us; speedup vs baseline: 1.1006x; 1.1006x over previous
//
#include <hip/hip_runtime.h>
#include <math.h>

#define PI_F 3.14159265358979323846f

typedef __attribute__((ext_vector_type(8))) short short8;
typedef __attribute__((ext_vector_type(4))) float f32x4;

__device__ __forceinline__ unsigned short f2bf(float f) {
    unsigned int u = __float_as_uint(f);
    unsigned int r = (u + 0x7fffu + ((u >> 16) & 1u)) >> 16;
    return (unsigned short)r;
}
__device__ __forceinline__ float bf2f(unsigned short v) {
    return __uint_as_float((unsigned int)v << 16);
}

// ---------------- encoder: x[16][8192][2] -> u1 bf16 [64][16][8192] ----------------
__global__ __launch_bounds__(256) void enc_kernel(
    const float* __restrict__ x, const float* __restrict__ ew,
    const float* __restrict__ eb, unsigned short* __restrict__ u1)
{
    int idx = blockIdx.x * 256 + threadIdx.x;   // 64*16*2048 threads, 4 t each
    int t4 = idx & 2047;
    int b  = (idx >> 11) & 15;
    int h  = idx >> 15;
    float w0 = ew[2*h], w1 = ew[2*h+1], bb = eb[h];
    const float* xp = x + ((size_t)b*8192 + (size_t)t4*4)*2;
    float4 a = *(const float4*)xp;
    float4 c = *(const float4*)(xp + 4);
    ushort4 o;
    o.x = f2bf(fmaf(w0, a.x, fmaf(w1, a.y, bb)));
    o.y = f2bf(fmaf(w0, a.z, fmaf(w1, a.w, bb)));
    o.z = f2bf(fmaf(w0, c.x, fmaf(w1, c.y, bb)));
    o.w = f2bf(fmaf(w0, c.z, fmaf(w1, c.w, bb)));
    *(ushort4*)(u1 + ((size_t)h*16 + b)*8192 + (size_t)t4*4) = o;
}

// ---------------- conv weight prep: fp32 [O][Cin][3] -> bf16 A-frag [kb][o][kk] ------
__global__ __launch_bounds__(256) void prep_w(
    const float* __restrict__ w0, const float* __restrict__ w1,
    const float* __restrict__ w2, const float* __restrict__ w3,
    const float* __restrict__ w4, const float* __restrict__ w5,
    const float* __restrict__ w6, const float* __restrict__ w7,
    unsigned short* __restrict__ wprep)
{
    int id = blockIdx.y;
    const float* src; int Cin; size_t doff;
    switch (id) {
        case 0: src = w0; Cin = 64;  doff = 0;      break;
        case 1: src = w1; Cin = 64;  doff = 12288;  break;
        case 2: src = w2; Cin = 64;  doff = 24576;  break;
        case 3: src = w3; Cin = 64;  doff = 36864;  break;
        case 4: src = w4; Cin = 256; doff = 49152;  break;
        case 5: src = w5; Cin = 256; doff = 245760; break;
        case 6: src = w6; Cin = 256; doff = 442368; break;
        default: src = w7; Cin = 256; doff = 638976; break;
    }
    int e = blockIdx.x * 256 + threadIdx.x;
    if (e >= Cin * Cin * 3) return;
    int kb  = e / (Cin * 32);
    int rem = e - kb * (Cin * 32);
    int o   = rem >> 5;
    int kk  = rem & 31;
    int cch = kb / 6, t6 = kb % 6, k = t6 >> 1, chalf = t6 & 1;
    int c = cch * 64 + chalf * 32 + kk;
    wprep[doff + e] = f2bf(src[((size_t)o * Cin + c) * 3 + k]);
}

// ---------------- S4 prep: build per-h MFMA A-matrices (coalesced writes) ----------
__global__ __launch_bounds__(128) void prep_s4(
    const float* __restrict__ log_dt, const float* __restrict__ C2,
    const float* __restrict__ Dv,
    unsigned short* __restrict__ TA, unsigned short* __restrict__ VA,
    float* __restrict__ rs, float* __restrict__ Vrs)
{
    int h = blockIdx.x, t = threadIdx.x;
    __shared__ float cn[64];
    __shared__ float sK[128];
    __shared__ unsigned short s_w[128 * 66];   // W staged [m][j], pad 66
    float dt = expf(log_dt[h]);
    if (t < 32) {
        int n = t;
        float e = expf(-0.5f*dt);
        float s_, c_; sincosf(PI_F*dt*n, &s_, &c_);
        float wr = e*c_, wi = e*s_;
        float ar = -0.5f, ai = PI_F*n;
        float den = 1.f/(ar*ar + ai*ai);
        float tr = wr - 1.f, ti = wi;
        float qr = (tr*ar + ti*ai)*den;
        float qi = (ti*ar - tr*ai)*den;
        float c2r = C2[((size_t)h*32+n)*2], c2i = C2[((size_t)h*32+n)*2+1];
        cn[2*n]   = 2.f*(c2r*qr - c2i*qi);
        cn[2*n+1] = 2.f*(c2r*qi + c2i*qr);
        float e128 = expf(-64.f*dt);
        float s2, c2v; sincosf(PI_F*dt*n*128.f, &s2, &c2v);
        float pr = 1.f - e128*c2v, pim = -e128*s2;
        float dr = 1.f - wr, di = -wi;
        float dd = 1.f/(dr*dr + di*di);
        Vrs[(size_t)h*64 + 2*n]   = (pr*dr + pim*di)*dd;
        Vrs[(size_t)h*64 + 2*n+1] = (pim*dr - pr*di)*dd;
    }
    __syncthreads();
    {
        float em = expf(-0.5f*dt*t);
        float Kt = 0.f;
        for (int n = 0; n < 32; n++) {
            float s_, c_; sincosf(PI_F*dt*(float)(n*t), &s_, &c_);
            Kt += cn[2*n]*em*c_ - cn[2*n+1]*em*s_;
        }
        sK[t] = Kt + (t == 0 ? Dv[h] : 0.f);
    }
    if (t < 64) {
        int n = t >> 1, ri = t & 1;
        float e = expf(-0.5f*dt);
        float s_, c_; sincosf(PI_F*dt*n, &s_, &c_);
        float wr = e*c_, wi = e*s_;
        float crn = cn[2*n], cin = cn[2*n+1];
        float pr = wr, pim = wi;
        for (int m = 0; m < 128; m++) {
            float re = crn*pr - cin*pim;
            float im = crn*pim + cin*pr;
            s_w[m*66 + t] = f2bf(ri ? -im : re);
            float nr = pr*wr - pim*wi;
            float ni = pr*wi + pim*wr;
            pr = nr; pim = ni;
        }
    } else {
        int r = t - 64; int n = r >> 1, ri = r & 1;
        float e = expf(-0.5f*dt);
        float s_, c_; sincosf(PI_F*dt*n, &s_, &c_);
        float wr = e*c_, wi = e*s_;
        float cr2 = 1.f, ci2 = 0.f;
        for (int kb = 3; kb >= 0; kb--) {
            unsigned short buf[32];
            for (int kk = 31; kk >= 0; kk--) {
                buf[kk] = f2bf(ri ? ci2 : cr2);
                float nr = cr2*wr - ci2*wi;
                float ni = cr2*wi + ci2*wr;
                cr2 = nr; ci2 = ni;
            }
            uint4* dst = (uint4*)&VA[(((size_t)h*4 + kb)*64 + r)*32];
            uint4* src = (uint4*)buf;
            dst[0]=src[0]; dst[1]=src[1]; dst[2]=src[2]; dst[3]=src[3];
        }
    }
    __syncthreads();
    {
        float acc = 0.f;
        for (int tau = 0; tau <= t; tau++) acc += sK[tau];
        rs[(size_t)h*128 + t] = acc;
    }
    for (int kb = 0; kb < 4; kb++) {
        unsigned short tb[32];
#pragma unroll
        for (int kk = 0; kk < 32; kk++) {
            int col = kb*32 + kk;
            tb[kk] = f2bf((col <= t) ? sK[t - col] : 0.f);
        }
        uint4* dst = (uint4*)&TA[(((size_t)h*6 + kb)*128 + t)*32];
        uint4* src = (uint4*)tb;
        dst[0]=src[0]; dst[1]=src[1]; dst[2]=src[2]; dst[3]=src[3];
    }
    for (int i = t; i < 1024; i += 128) {
        int kb = i >> 9;
        int rem = i & 511;
        int m = rem >> 2, kkg = rem & 3;
        *(uint4*)&TA[(((size_t)h*6 + 4 + kb)*128 + m)*32 + kkg*8] =
            *(const uint4*)&s_w[m*66 + kb*32 + kkg*8];
    }
}

// ---------------- slim prep (s4c): V rows + rowsums, coalesced ----------------
__global__ __launch_bounds__(64) void prep_va(
    const float* __restrict__ log_dt,
    unsigned short* __restrict__ VA, float* __restrict__ Vrs)
{
    int h = blockIdx.x, t = threadIdx.x;     // t = row = 2n+ri
    int n = t >> 1, ri = t & 1;
    float dt = expf(log_dt[h]);
    float e = expf(-0.5f*dt);
    float s_, c_; sincosf(PI_F*dt*n, &s_, &c_);
    float wr = e*c_, wi = e*s_;
    float cr2 = 1.f, ci2 = 0.f;
    for (int kb = 3; kb >= 0; kb--) {
        unsigned short buf[32];
        for (int kk = 31; kk >= 0; kk--) {
            buf[kk] = f2bf(ri ? ci2 : cr2);
            float nr = cr2*wr - ci2*wi;
            float ni = cr2*wi + ci2*wr;
            cr2 = nr; ci2 = ni;
        }
        uint4* dst = (uint4*)&VA[(((size_t)h*4 + kb)*64 + t)*32];
        uint4* src = (uint4*)buf;
        dst[0]=src[0]; dst[1]=src[1]; dst[2]=src[2]; dst[3]=src[3];
    }
    if (ri == 0) {
        float e128 = expf(-64.f*dt);
        float s2, c2v; sincosf(PI_F*dt*n*128.f, &s2, &c2v);
        float pr = 1.f - e128*c2v, pim = -e128*s2;
        float dr = 1.f - wr, di = -wi;
        float dd = 1.f/(dr*dr + di*di);
        Vrs[(size_t)h*64 + 2*n]   = (pr*dr + pim*di)*dd;
        Vrs[(size_t)h*64 + 2*n+1] = (pim*dr - pr*di)*dd;
    }
}

// ---------------- S4 pass A (GEMM): chunk end-states E = V @ u ----------------
template<int NCH, int LOGNCH>
__global__ __launch_bounds__(64) void s4_gemm_a(
    const unsigned short* __restrict__ u, const unsigned short* __restrict__ VA,
    const float* __restrict__ Vrs, const float* __restrict__ sc,
    const float* __restrict__ sh, float* __restrict__ Bc)
{
    const int L = NCH * 128;
    int h = blockIdx.y;
    int lane = threadIdx.x;
    int nl = lane & 15, g = lane >> 4;
    int col = blockIdx.x * 16 + nl;
    int b = col >> LOGNCH, c = col & (NCH - 1);
    const unsigned short* up = u + ((size_t)h*16 + b)*L + c*128;
    f32x4 acc[4];
#pragma unroll
    for (int mt = 0; mt < 4; mt++) acc[mt] = (f32x4){0.f,0.f,0.f,0.f};
#pragma unroll
    for (int kb = 0; kb < 4; kb++) {
        short8 bf = *(const short8*)(up + kb*32 + g*8);
#pragma unroll
        for (int mt = 0; mt < 4; mt++) {
            short8 af = *(const short8*)(VA + (((size_t)h*4 + kb)*64 + mt*16 + nl)*32 + g*8);
            acc[mt] = __builtin_amdgcn_mfma_f32_16x16x32_bf16(af, bf, acc[mt], 0, 0, 0);
        }
    }
    float scv = sc ? sc[h] : 1.f;
    float shv = sh ? sh[h] : 0.f;
    float* bp = Bc + (((size_t)h*16 + b)*NCH + c)*64;
#pragma unroll
    for (int mt = 0; mt < 4; mt++) {
        int j0 = mt*16 + g*4;
        float4 vr = *(const float4*)(Vrs + (size_t)h*64 + j0);
        float4 o;
        o.x = fmaf(scv, acc[mt][0], shv*vr.x);
        o.y = fmaf(scv, acc[mt][1], shv*vr.y);
        o.z = fmaf(scv, acc[mt][2], shv*vr.z);
        o.w = fmaf(scv, acc[mt][3], shv*vr.w);
        *(float4*)(bp + j0) = o;
    }
}

// ---------------- S4 mid: chunk-level scan (w^128 via 7 squarings) ----------------
__global__ __launch_bounds__(64) void s4_mid(
    const float* __restrict__ log_dt, const float* __restrict__ Bc,
    float* __restrict__ Sinit, float* __restrict__ Sfinal,
    int H, int NCH)
{
    int gid = blockIdx.x * 64 + threadIdx.x;   // H*16*32
    int n = gid & 31;
    int tmp = gid >> 5;
    int b = tmp & 15;
    int h = tmp >> 4;
    float dt = expf(log_dt[h]);
    float e = expf(-0.5f * dt);
    float s_, c_; sincosf(PI_F * dt * n, &s_, &c_);
    float wr = e * c_, wi = e * s_;
#pragma unroll
    for (int i = 0; i < 7; i++) { float r = wr*wr - wi*wi; float im = 2.f*wr*wi; wr = r; wi = im; }
    float Sr = 0.f, Si = 0.f;
    size_t base = (((size_t)h*16 + b)*NCH)*64 + 2*n;
    for (int c = 0; c < NCH; c++) {
        float2 v; v.x = Sr; v.y = Si;
        *(float2*)(Sinit + base + (size_t)c*64) = v;
        float2 bc = *(const float2*)(Bc + base + (size_t)c*64);
        float r  = fmaf(wr, Sr, fmaf(-wi, Si, bc.x));
        float im = fmaf(wi, Sr, fmaf( wr, Si, bc.y));
        Sr = r; Si = im;
    }
    if (Sfinal) {
        float2 v; v.x = Sr; v.y = Si;
        *(float2*)(Sfinal + ((size_t)h*16 + b)*64 + 2*n) = v;
    }
}

// ---------------- S4 pass C (GEMM): y = sc*(T'@u) + sh*rs + W@Sinit ----------------
template<int NCH, int LOGNCH>
__global__ __launch_bounds__(256) void s4_gemm_c(
    const unsigned short* __restrict__ u, const float* __restrict__ Sini,
    const unsigned short* __restrict__ TA, const float* __restrict__ rs,
    const float* __restrict__ sc, const float* __restrict__ sh,
    unsigned short* __restrict__ yout)
{
    const int L = NCH * 128;
    __shared__ unsigned short s_u[64*200];   // 25600 B
    __shared__ unsigned short s_s[64*72];    // 9216 B
    int h = blockIdx.y;
    int tid = threadIdx.x;
    int lane = tid & 63, wid = tid >> 6;
    int nl = lane & 15, g = lane >> 4;
    int col0 = blockIdx.x * 64;
    for (int i = tid; i < 1024; i += 256) {
        int cl = i >> 4, o = i & 15;
        int col = col0 + cl; int b = col >> LOGNCH, c = col & (NCH - 1);
        *(uint4*)&s_u[cl*200 + o*8] =
            *(const uint4*)&u[((size_t)h*16 + b)*L + c*128 + o*8];
    }
    for (int i = tid; i < 1024; i += 256) {
        int cl = i >> 4, o = i & 15;
        int col = col0 + cl; int b = col >> LOGNCH, c = col & (NCH - 1);
        float4 v = *(const float4*)&Sini[(((size_t)h*16 + b)*NCH + c)*64 + o*4];
        ushort4 q; q.x = f2bf(v.x); q.y = f2bf(v.y); q.z = f2bf(v.z); q.w = f2bf(v.w);
        *(ushort4*)&s_s[cl*72 + o*4] = q;
    }
    __syncthreads();
    f32x4 accT[2][4], accW[2][4];
#pragma unroll
    for (int a = 0; a < 2; a++)
#pragma unroll
        for (int j = 0; j < 4; j++) { accT[a][j] = (f32x4){0,0,0,0}; accW[a][j] = (f32x4){0,0,0,0}; }
#pragma unroll
    for (int kb = 0; kb < 4; kb++) {
        short8 bfr[4];
#pragma unroll
        for (int j = 0; j < 4; j++)
            bfr[j] = *(const short8*)&s_u[(j*16 + nl)*200 + kb*32 + g*8];
#pragma unroll
        for (int mt2 = 0; mt2 < 2; mt2++) {
            int mtile = wid*2 + mt2;
            short8 af = *(const short8*)&TA[(((size_t)h*6 + kb)*128 + mtile*16 + nl)*32 + g*8];
#pragma unroll
            for (int j = 0; j < 4; j++)
                accT[mt2][j] = __builtin_amdgcn_mfma_f32_16x16x32_bf16(af, bfr[j], accT[mt2][j], 0, 0, 0);
        }
    }
#pragma unroll
    for (int kw = 0; kw < 2; kw++) {
        short8 bfr[4];
#pragma unroll
        for (int j = 0; j < 4; j++)
            bfr[j] = *(const short8*)&s_s[(j*16 + nl)*72 + kw*32 + g*8];
#pragma unroll
        for (int mt2 = 0; mt2 < 2; mt2++) {
            int mtile = wid*2 + mt2;
            short8 af = *(const short8*)&TA[(((size_t)h*6 + 4 + kw)*128 + mtile*16 + nl)*32 + g*8];
#pragma unroll
            for (int j = 0; j < 4; j++)
                accW[mt2][j] = __builtin_amdgcn_mfma_f32_16x16x32_bf16(af, bfr[j], accW[mt2][j], 0, 0, 0);
        }
    }
    float scv = sc ? sc[h] : 1.f;
    float shv = sh ? sh[h] : 0.f;
#pragma unroll
    for (int mt2 = 0; mt2 < 2; mt2++) {
        int m0 = (wid*2 + mt2)*16 + g*4;
        float4 rsv = *(const float4*)&rs[(size_t)h*128 + m0];
#pragma unroll
        for (int j = 0; j < 4; j++) {
            int col = col0 + j*16 + nl; int b = col >> LOGNCH, c = col & (NCH - 1);
            ushort4 q;
            q.x = f2bf(fmaf(scv, accT[mt2][j][0], shv*rsv.x) + accW[mt2][j][0]);
            q.y = f2bf(fmaf(scv, accT[mt2][j][1], shv*rsv.y) + accW[mt2][j][1]);
            q.z = f2bf(fmaf(scv, accT[mt2][j][2], shv*rsv.z) + accW[mt2][j][2]);
            q.w = f2bf(fmaf(scv, accT[mt2][j][3], shv*rsv.w) + accW[mt2][j][3]);
            *(ushort4*)&yout[((size_t)h*16 + b)*L + c*128 + m0] = q;
        }
    }
}

// ---------------- fused 4-dilation conv block via MFMA (v5) ----------------
// block = 32 o x 64 t x 4 d, og-split grid (4 blocks/CU by LDS);
// launch_bounds (256,2): do NOT force the allocator under the working set —
// (256,4) split the unified file 64 arch + 64 acc and spilled 135 MB/dispatch (R8).
template<int CIN>
__global__ __launch_bounds__(256, 2) void conv_mfma4(
    const unsigned short* __restrict__ u, const unsigned short* __restrict__ wp,
    const float* __restrict__ bs0, const float* __restrict__ bs1,
    const float* __restrict__ bs2, const float* __restrict__ bs3,
    unsigned short* __restrict__ out, int Lin, int Lout)
{
    constexpr int NR = CIN / 64;
    constexpr int PWP = 74;                    // padded row (ushorts), 37 words
    __shared__ unsigned short s_in[4*68*PWP];  // 40256 B -> 4 blocks/CU
    int tid = threadIdx.x;
    int lane = tid & 63, wid = tid >> 6;
    int ow = wid & 1, fh = wid >> 1;
    int nl = lane & 15, g = lane >> 4;
    int t0 = blockIdx.x * 64;
    int b  = blockIdx.y;
    int og = blockIdx.z * 32;
    const int P0 = t0 * 4 - 8;

    f32x4 acc[4][2];   // [d][f]
#pragma unroll
    for (int d = 0; d < 4; d++)
#pragma unroll
        for (int f = 0; f < 2; f++) acc[d][f] = (f32x4){0.f,0.f,0.f,0.f};

    // staging descriptors: i = tid + 256*j; ch = i & 63 (lane order), po = i >> 6
    unsigned short stg[9][8];
    int sch[9], spo[9];
#pragma unroll
    for (int j = 0; j < 9; j++) { int i = tid + 256*j; sch[j] = i & 63; spo[j] = i >> 6; }
    const bool v8 = (tid < 128);   // 2176 slots; slot 8 valid for tid<128

    // prologue: load round 0
#pragma unroll
    for (int j = 0; j < 9; j++) {
        if (j == 8 && !v8) continue;
        int p = P0 + spo[j]*8;
        const unsigned short* gp = u + ((size_t)sch[j]*16 + b)*Lin;
        if (p >= 0 && p + 8 <= Lin) {
            *(uint4*)stg[j] = *(const uint4*)(gp + p);
        } else {
#pragma unroll
            for (int jj = 0; jj < 8; jj++) {
                int pj = p + jj;
                stg[j][jj] = ((unsigned)pj < (unsigned)Lin) ? gp[pj] : (unsigned short)0;
            }
        }
    }

    for (int cc = 0; cc < NR; cc++) {
        if (cc) __syncthreads();
#pragma unroll
        for (int j = 0; j < 9; j++) {
            if (j == 8 && !v8) continue;
#pragma unroll
            for (int jj = 0; jj < 8; jj++)
                s_in[((jj&3)*68 + spo[j]*2 + (jj>>2))*PWP + sch[j]] = stg[j][jj];
        }
        __syncthreads();
        if (cc + 1 < NR) {
#pragma unroll
            for (int j = 0; j < 9; j++) {
                if (j == 8 && !v8) continue;
                int p = P0 + spo[j]*8;
                const unsigned short* gp = u + ((size_t)((cc+1)*64 + sch[j])*16 + b)*Lin;
                if (p >= 0 && p + 8 <= Lin) {
                    *(uint4*)stg[j] = *(const uint4*)(gp + p);
                } else {
#pragma unroll
                    for (int jj = 0; jj < 8; jj++) {
                        int pj = p + jj;
                        stg[j][jj] = ((unsigned)pj < (unsigned)Lin) ? gp[pj] : (unsigned short)0;
                    }
                }
            }
        }
#pragma unroll
        for (int k = 0; k < 3; ++k) {
#pragma unroll
            for (int chalf = 0; chalf < 2; ++chalf) {
                int kb = cc*6 + k*2 + chalf;
                short8 af[4];
#pragma unroll
                for (int d = 0; d < 4; d++)
                    af[d] = *(const short8*)&wp[(size_t)d*(3*CIN*CIN) +
                        ((size_t)kb*CIN + og + ow*16 + nl)*32 + g*8];
                if (k == 1) {
                    short8 bf[2];
#pragma unroll
                    for (int f = 0; f < 2; f++)
                        bf[f] = *(const short8*)&s_in[(fh*32 + f*16 + nl + 2)*PWP + chalf*32 + g*8];
#pragma unroll
                    for (int d = 0; d < 4; d++)
#pragma unroll
                        for (int f = 0; f < 2; f++)
                            acc[d][f] = __builtin_amdgcn_mfma_f32_16x16x32_bf16(
                                af[d], bf[f], acc[d][f], 0, 0, 0);
                } else {
#pragma unroll
                    for (int d = 0; d < 4; d++) {
                        const int off = (k - 1) * (1 << d) + 8;   // 0..16
                        const int r = off & 3, s = off >> 2;
#pragma unroll
                        for (int f = 0; f < 2; f++) {
                            short8 bf = *(const short8*)&s_in[
                                (r*68 + fh*32 + f*16 + nl + s)*PWP + chalf*32 + g*8];
                            acc[d][f] = __builtin_amdgcn_mfma_f32_16x16x32_bf16(
                                af[d], bf, acc[d][f], 0, 0, 0);
                        }
                    }
                }
            }
        }
    }
    const float* bptr[4] = {bs0, bs1, bs2, bs3};
#pragma unroll
    for (int d = 0; d < 4; ++d) {
#pragma unroll
        for (int f = 0; f < 2; ++f) {
            int t = t0 + fh*32 + f*16 + nl;
#pragma unroll
            for (int r2 = 0; r2 < 4; ++r2) {
                int o = og + ow*16 + g*4 + r2;
                float v = acc[d][f][r2] + bptr[d][o];
                if (d) v = v >= 0.f ? v : 0.3f*v;
                out[((size_t)(d*CIN + o)*16 + b)*Lout + t] = f2bf(v);
            }
        }
    }
}

// ---------------- BN stats, two-stage ----------------
__global__ __launch_bounds__(256) void bn_sum(
    const unsigned short* __restrict__ x, float* __restrict__ part, int n, int nseg)
{
    int ch = blockIdx.x, seg = blockIdx.y;
    int m = n / nseg;
    const unsigned short* xp = x + (size_t)ch*n + (size_t)seg*m;
    float s1 = 0.f, s2 = 0.f;
    for (int i = threadIdx.x*8; i < m; i += 2048) {
        uint4 raw = *(const uint4*)(xp + i);
        unsigned short us[8]; *(uint4*)us = raw;
#pragma unroll
        for (int j = 0; j < 8; j++) {
            float v = bf2f(us[j]);
            s1 += v; s2 += v*v;
        }
    }
    for (int o = 32; o > 0; o >>= 1) { s1 += __shfl_down(s1, o); s2 += __shfl_down(s2, o); }
    __shared__ float p1[4], p2[4];
    int wid = threadIdx.x >> 6;
    if ((threadIdx.x & 63) == 0) { p1[wid] = s1; p2[wid] = s2; }
    __syncthreads();
    if (threadIdx.x == 0) {
        part[((size_t)ch*nseg + seg)*2]     = p1[0] + p1[1] + p1[2] + p1[3];
        part[((size_t)ch*nseg + seg)*2 + 1] = p2[0] + p2[1] + p2[2] + p2[3];
    }
}

__global__ __launch_bounds__(64) void bn_fin(
    const float* __restrict__ part, const float* __restrict__ g,
    const float* __restrict__ bb, float* __restrict__ sc, float* __restrict__ sh,
    int n, int nseg, int gmask)
{
    int ch = blockIdx.x*64 + threadIdx.x;
    float s1 = 0.f, s2 = 0.f;
    for (int s = 0; s < nseg; s++) {
        s1 += part[((size_t)ch*nseg + s)*2];
        s2 += part[((size_t)ch*nseg + s)*2 + 1];
    }
    float m = s1 / n;
    float var = s2 / n - m*m;
    float rstd = rsqrtf(var + 1e-5f);
    float scale = g[ch & gmask] * rstd;
    sc[ch] = scale;
    sh[ch] = fmaf(-m, scale, bb[ch & gmask]);
}

// ---------------- s4c final-state -> x3[:, :, 511] ----------------
__global__ __launch_bounds__(256) void s4c_last(
    const float* __restrict__ Sfinal, const unsigned short* __restrict__ u3,
    const float* __restrict__ sc, const float* __restrict__ sh,
    const float* __restrict__ log_dt, const float* __restrict__ C2,
    const float* __restrict__ Dv, float* __restrict__ x3last)
{
    int gid = blockIdx.x*256 + threadIdx.x;  // 16*1024
    int h = gid & 1023;
    int b = gid >> 10;
    float dt = expf(log_dt[h]);
    float e = expf(-0.5f * dt);
    const float* sp = Sfinal + ((size_t)h*16 + b)*64;
    float aR = 0.f, aI = 0.f;
#pragma unroll
    for (int n = 0; n < 32; n++) {
        float s_, c_; sincosf(PI_F * dt * n, &s_, &c_);
        float wr = e*c_, wi = e*s_;
        float ar = -0.5f, ai = PI_F * n;
        float den = 1.f / (ar*ar + ai*ai);
        float tr = wr - 1.f, ti = wi;
        float qr = (tr*ar + ti*ai) * den;
        float qi = (ti*ar - tr*ai) * den;
        float c2r = C2[((size_t)h*32 + n)*2], c2i = C2[((size_t)h*32 + n)*2 + 1];
        float crv = c2r*qr - c2i*qi, civ = c2r*qi + c2i*qr;
        aR = fmaf(crv, sp[2*n],   aR);
        aI = fmaf(civ, sp[2*n+1], aI);
    }
    float uv = fmaf(sc[h], bf2f(u3[((size_t)h*16 + b)*512 + 511]), sh[h]);
    x3last[b*1024 + h] = 2.f*(aR - aI) + Dv[h]*uv;
}

// ---------------- decoder head ----------------
__global__ __launch_bounds__(256) void dec_kernel(
    const float* __restrict__ x3last, const float* __restrict__ w1, const float* __restrict__ b1,
    const float* __restrict__ w2, const float* __restrict__ b2, float* __restrict__ out)
{
    __shared__ float xs[1024];
    int b = blockIdx.x, tid = threadIdx.x;
    for (int i = tid; i < 1024; i += 256) xs[i] = x3last[b*1024 + i];
    __syncthreads();
    float z = b1[tid];
    const float* wpt = w1 + (size_t)tid*1024;
    for (int i = 0; i < 1024; i += 4) {
        float4 wv = *(const float4*)(wpt + i);
        z = fmaf(wv.x, xs[i],   z);
        z = fmaf(wv.y, xs[i+1], z);
        z = fmaf(wv.z, xs[i+2], z);
        z = fmaf(wv.w, xs[i+3], z);
    }
    float v = w2[tid] * z;
    for (int o = 32; o > 0; o >>= 1) v += __shfl_down(v, o);
    __shared__ float ps[4];
    if ((tid & 63) == 0) ps[tid >> 6] = v;
    __syncthreads();
    if (tid == 0) out[b] = ps[0] + ps[1] + ps[2] + ps[3] + b2[0];
}

extern "C" void kernel_launch(void* const* d_in, const int* in_sizes, int n_in,
                              void* d_out, int out_size, void* d_ws, size_t ws_size,
                              hipStream_t stream)
{
    const float* x       = (const float*)d_in[0];
    const float* enc_w   = (const float*)d_in[1];
    const float* enc_b   = (const float*)d_in[2];
    const float* s4a_ldt = (const float*)d_in[3];
    const float* s4a_C   = (const float*)d_in[4];
    const float* s4a_D   = (const float*)d_in[5];
    const float* s4b_ldt = (const float*)d_in[6];
    const float* s4b_C   = (const float*)d_in[7];
    const float* s4b_D   = (const float*)d_in[8];
    const float* s4c_ldt = (const float*)d_in[9];
    const float* s4c_C   = (const float*)d_in[10];
    const float* s4c_D   = (const float*)d_in[11];
    const float* b1w[4] = {(const float*)d_in[12], (const float*)d_in[14], (const float*)d_in[16], (const float*)d_in[18]};
    const float* b1b[4] = {(const float*)d_in[13], (const float*)d_in[15], (const float*)d_in[17], (const float*)d_in[19]};
    const float* b2w[4] = {(const float*)d_in[20], (const float*)d_in[22], (const float*)d_in[24], (const float*)d_in[26]};
    const float* b2b[4] = {(const float*)d_in[21], (const float*)d_in[23], (const float*)d_in[25], (const float*)d_in[27]};
    const float* bn1_g  = (const float*)d_in[28];
    const float* bn1_b  = (const float*)d_in[29];
    const float* bn2_g  = (const float*)d_in[30];
    const float* bn2_b  = (const float*)d_in[31];
    const float* dec1_w = (const float*)d_in[32];
    const float* dec1_b = (const float*)d_in[33];
    const float* dec2_w = (const float*)d_in[34];
    const float* dec2_b = (const float*)d_in[35];
    float* out = (float*)d_out;

    char* ws = (char*)d_ws;
    unsigned short* u1    = (unsigned short*)(ws);              // 16.8 MB (also u3)
    unsigned short* u3    = u1;
    unsigned short* ya    = (unsigned short*)(ws + 16777216);   // 16.8 MB (also yb, later VA_c)
    unsigned short* yb    = ya;
    unsigned short* VA_c  = ya;                                 // reuse after conv2
    unsigned short* u2    = (unsigned short*)(ws + 33554432);   // 16.8 MB
    float*          Bc    = (float*)(ws + 50331648);            // 16.8 MB
    float*          Sini  = (float*)(ws + 67108864);            // 16.8 MB
    float*          Sfin  = (float*)(ws + 83886080);            // 4.2 MB
    unsigned short* wprep = (unsigned short*)(ws + 88080384);   // 1.67 MB
    unsigned short* TA_a  = (unsigned short*)(ws + 89751552);   // 3.15 MB
    unsigned short* TA_b  = (unsigned short*)(ws + 92897280);   // 12.6 MB
    unsigned short* VA_a  = (unsigned short*)(ws + 105480192);  // 1.05 MB
    unsigned short* VA_b  = (unsigned short*)(ws + 106528768);  // 4.2 MB
    float*          rs_a  = (float*)(ws + 110723072);           // 32 KB
    float*          rs_b  = (float*)(ws + 110755840);           // 128 KB
    float*          Vrs_a = (float*)(ws + 110886912);           // 16 KB
    float*          Vrs_b = (float*)(ws + 110903296);           // 64 KB
    float*          smallp= (float*)(ws + 110968832);
    float* sc1 = smallp;         // 256
    float* sh1 = smallp + 256;   // 256
    float* sc2 = smallp + 512;   // 1024
    float* sh2 = smallp + 1536;  // 1024
    float* x3l = smallp + 2560;  // 16384
    float*          Vrs_c = (float*)(ws + 111280128);           // 256 KB
    float*          part1 = (float*)(ws + 111542272);           // 16 KB (256*8*2)
    float*          part2 = (float*)(ws + 111558656);           // 16 KB (1024*2*2)

    // prep (independent of data path)
    prep_w<<<dim3(768, 8), 256, 0, stream>>>(b1w[0], b1w[1], b1w[2], b1w[3],
                                             b2w[0], b2w[1], b2w[2], b2w[3], wprep);
    prep_s4<<<64, 128, 0, stream>>>(s4a_ldt, s4a_C, s4a_D, TA_a, VA_a, rs_a, Vrs_a);
    prep_s4<<<256, 128, 0, stream>>>(s4b_ldt, s4b_C, s4b_D, TA_b, VA_b, rs_b, Vrs_b);

    // encoder -> u1 bf16
    enc_kernel<<<8192, 256, 0, stream>>>(x, enc_w, enc_b, u1);

    // s4a: H=64, NCH=64 (L=8192)
    s4_gemm_a<64,6><<<dim3(64, 64), 64, 0, stream>>>(u1, VA_a, Vrs_a, nullptr, nullptr, Bc);
    s4_mid<<<512, 64, 0, stream>>>(s4a_ldt, Bc, Sini, nullptr, 64, 64);
    s4_gemm_c<64,6><<<dim3(16, 64), 256, 0, stream>>>(u1, Sini, TA_a, rs_a, nullptr, nullptr, ya);

    // conv block1 (fused 4 dilations, og-split): ya [64][16][8192] -> u2 [256][16][2048]
    conv_mfma4<64><<<dim3(32, 16, 2), 256, 0, stream>>>(
        ya, wprep, b1b[0], b1b[1], b1b[2], b1b[3], u2, 8192, 2048);
    bn_sum<<<dim3(256, 8), 256, 0, stream>>>(u2, part1, 16*2048, 8);
    bn_fin<<<4, 64, 0, stream>>>(part1, bn1_g, bn1_b, sc1, sh1, 16*2048, 8, 63);

    // s4b: H=256, NCH=16 (L=2048)
    s4_gemm_a<16,4><<<dim3(16, 256), 64, 0, stream>>>(u2, VA_b, Vrs_b, sc1, sh1, Bc);
    s4_mid<<<2048, 64, 0, stream>>>(s4b_ldt, Bc, Sini, nullptr, 256, 16);
    s4_gemm_c<16,4><<<dim3(4, 256), 256, 0, stream>>>(u2, Sini, TA_b, rs_b, sc1, sh1, yb);

    // conv block2 (fused 4 dilations, og-split): yb [256][16][2048] -> u3 [1024][16][512]
    conv_mfma4<256><<<dim3(8, 16, 8), 256, 0, stream>>>(
        yb, wprep + 49152, b2b[0], b2b[1], b2b[2], b2b[3], u3, 2048, 512);
    bn_sum<<<dim3(1024, 2), 256, 0, stream>>>(u3, part2, 16*512, 2);
    bn_fin<<<16, 64, 0, stream>>>(part2, bn2_g, bn2_b, sc2, sh2, 16*512, 2, 255);

    // s4c: H=1024, NCH=4 (L=512); only final state needed.
    prep_va<<<1024, 64, 0, stream>>>(s4c_ldt, VA_c, Vrs_c);
    s4_gemm_a<4,2><<<dim3(4, 1024), 64, 0, stream>>>(u3, VA_c, Vrs_c, sc2, sh2, Bc);
    s4_mid<<<8192, 64, 0, stream>>>(s4c_ldt, Bc, Sini, Sfin, 1024, 4);
    s4c_last<<<64, 256, 0, stream>>>(Sfin, u3, sc2, sh2, s4c_ldt, s4c_C, s4c_D, x3l);

    // decoder head
    dec_kernel<<<16, 256, 0, stream>>>(x3l, dec1_w, dec1_b, dec2_w, dec2_b, out);
}